// Round 1
// baseline (516.724 us; speedup 1.0000x reference)
//
#include <hip/hip_runtime.h>

#define HW 3136
#define CH 256
#define CR 64

// Kernel A: y = relu(bn(w1 @ x + b1)), stored transposed: yt[b*HW + h*56 + w][64]
__global__ __launch_bounds__(256) void ky(
    const float* __restrict__ x, const float* __restrict__ w1,
    const float* __restrict__ b1, const float* __restrict__ gamma,
    const float* __restrict__ beta, const float* __restrict__ mean,
    const float* __restrict__ var, float* __restrict__ yt)
{
    __shared__ float w1t[128 * 64];   // [c_local][o], 32 KB
    const int t = threadIdx.x;
    const int pix = t & 31;           // 32 pixels per block
    const int oq = t >> 5;            // 0..7, 8 outputs each
    const int P = blockIdx.x * 32 + pix;
    const int b = P / HW;
    const int p = P - b * HW;
    const float* xp = x + (size_t)b * CH * HW + p;

    float acc[8];
#pragma unroll
    for (int i = 0; i < 8; ++i) acc[i] = 0.f;

    for (int cb = 0; cb < 2; ++cb) {
        __syncthreads();
        // stage w1 transposed: w1t[cl*64+o] = w1[o*256 + cb*128 + cl]
        for (int L = t; L < 128 * 64; L += 256) {
            int o = L & 63, cl = L >> 6;
            w1t[L] = w1[o * 256 + cb * 128 + cl];
        }
        __syncthreads();
#pragma unroll 4
        for (int cl = 0; cl < 128; ++cl) {
            float xv = xp[(size_t)(cb * 128 + cl) * HW];
            float4 wa = *(const float4*)&w1t[cl * 64 + oq * 8];
            float4 wb = *(const float4*)&w1t[cl * 64 + oq * 8 + 4];
            acc[0] += wa.x * xv; acc[1] += wa.y * xv;
            acc[2] += wa.z * xv; acc[3] += wa.w * xv;
            acc[4] += wb.x * xv; acc[5] += wb.y * xv;
            acc[6] += wb.z * xv; acc[7] += wb.w * xv;
        }
    }

    const int o0 = oq * 8;
    float res[8];
#pragma unroll
    for (int i = 0; i < 8; ++i) {
        int o = o0 + i;
        float sc = gamma[o] * rsqrtf(var[o] + 1e-5f);
        float sh = beta[o] - mean[o] * sc;
        float v = (acc[i] + b1[o]) * sc + sh;
        res[i] = fmaxf(v, 0.f);
    }
    float4* yo = (float4*)(yt + (size_t)P * 64 + o0);
    yo[0] = make_float4(res[0], res[1], res[2], res[3]);
    yo[1] = make_float4(res[4], res[5], res[6], res[7]);
}

// Kernel B: fused weight-generation (w2 @ y + b2) + involution.
// Block: 256 threads = 16 pixels (4x4 tile) x 16 "sub" lanes.
// Loops over 16 group-chunks (4 groups = 196 weight channels = 16 x-channels each).
__global__ __launch_bounds__(256, 3) void kmain(
    const float* __restrict__ x, const float* __restrict__ w2,
    const float* __restrict__ b2, const float* __restrict__ yt,
    float* __restrict__ out)
{
    __shared__ float wgt[196 * 16];   // [chl][pix], 12.25 KB
    __shared__ float xs[16 * 110];    // 16 ch x 10 rows x stride-11, 6.9 KB
    const int t = threadIdx.x;
    const int pix = t & 15;           // 0..15
    const int sub = t >> 4;           // 0..15
    const int b = blockIdx.z;
    const int h0 = blockIdx.y * 4;
    const int w0 = blockIdx.x * 4;
    const int ph = pix >> 2, pw = pix & 3;
    const int h = h0 + ph, w = w0 + pw;

    // this pixel's y vector (64 floats) lives in registers for the whole block
    float4 yv[16];
    {
        const float4* yp = (const float4*)(yt + ((size_t)b * HW + h * 56 + w) * 64);
#pragma unroll
        for (int i = 0; i < 16; ++i) yv[i] = yp[i];
    }

#pragma unroll 1
    for (int gc = 0; gc < 16; ++gc) {
        // stage x footprint: channels gc*16..+15, rows h0-3..h0+6, cols w0-3..w0+6
#pragma unroll 1
        for (int L = t; L < 1600; L += 256) {
            int cl = L / 100;
            int rem = L - cl * 100;
            int r = rem / 10;
            int s = rem - r * 10;
            int hh = h0 + r - 3, ww = w0 + s - 3;
            float v = 0.f;
            if (hh >= 0 && hh < 56 && ww >= 0 && ww < 56)
                v = x[(((size_t)b * CH + gc * 16 + cl) * 56 + hh) * 56 + ww];
            xs[cl * 110 + r * 11 + s] = v;
        }
        // weight chunk: 196 channels x 16 pixels, each a 64-MAC dot with y (in regs)
#pragma unroll 1
        for (int chl = sub; chl < 196; chl += 16) {
            int ch = gc * 196 + chl;
            const float4* wrow = (const float4*)(w2 + (size_t)ch * 64);
            float a = b2[ch];
#pragma unroll
            for (int i = 0; i < 16; ++i) {
                float4 wv = wrow[i];
                a += wv.x * yv[i].x + wv.y * yv[i].y + wv.z * yv[i].z + wv.w * yv[i].w;
            }
            wgt[chl * 16 + pix] = a;
        }
        __syncthreads();
        // involution: one output (channel gc*16+sub, pixel pix) per thread
        {
            int oc = sub;             // 0..15 -> group local oc>>2, chan-in-group oc&3
            int gl = oc >> 2;
            float a = 0.f;
#pragma unroll
            for (int ki = 0; ki < 7; ++ki) {
#pragma unroll
                for (int kj = 0; kj < 7; ++kj) {
                    float wv = wgt[(gl * 49 + ki * 7 + kj) * 16 + pix];
                    float xv = xs[oc * 110 + (ph + ki) * 11 + (pw + kj)];
                    a += wv * xv;
                }
            }
            out[(((size_t)b * CH + gc * 16 + oc) * 56 + h) * 56 + w] = a;
        }
        __syncthreads();
    }
}

extern "C" void kernel_launch(void* const* d_in, const int* in_sizes, int n_in,
                              void* d_out, int out_size, void* d_ws, size_t ws_size,
                              hipStream_t stream) {
    const float* x     = (const float*)d_in[0];
    const float* w1    = (const float*)d_in[1];
    const float* b1    = (const float*)d_in[2];
    const float* gamma = (const float*)d_in[3];
    const float* beta  = (const float*)d_in[4];
    const float* mean  = (const float*)d_in[5];
    const float* var   = (const float*)d_in[6];
    const float* w2    = (const float*)d_in[7];
    const float* b2    = (const float*)d_in[8];
    float* out = (float*)d_out;
    float* yt  = (float*)d_ws;   // 4*3136*64 floats = 3.06 MB

    hipLaunchKernelGGL(ky, dim3(392), dim3(256), 0, stream,
                       x, w1, b1, gamma, beta, mean, var, yt);
    hipLaunchKernelGGL(kmain, dim3(14, 14, 4), dim3(256), 0, stream,
                       x, w2, b2, yt, out);
}

// Round 2
// 198.311 us; speedup vs baseline: 2.6056x; 2.6056x over previous
//
#include <hip/hip_runtime.h>

typedef short short8 __attribute__((ext_vector_type(8)));
typedef float f32x4 __attribute__((ext_vector_type(4)));

#define HW 3136   // 56*56, channel stride
#define NPX 12544 // B*HW

__device__ __forceinline__ unsigned short f2bf(float f) {
    union { float f; unsigned int u; } v; v.f = f;
    unsigned int u = v.u;
    u += 0x7FFFu + ((u >> 16) & 1u);
    return (unsigned short)(u >> 16);
}

// convert w2 (3136x64 fp32) -> bf16, row-major [ch][k]
__global__ __launch_bounds__(256) void kprep(const float* __restrict__ w2,
                                             unsigned short* __restrict__ w2b) {
    int i = (blockIdx.x * 256 + threadIdx.x) * 4;
    float4 v = *(const float4*)(w2 + i);
    ushort4 r;
    r.x = f2bf(v.x); r.y = f2bf(v.y); r.z = f2bf(v.z); r.w = f2bf(v.w);
    *(ushort4*)(w2b + i) = r;
}

// y = relu(bn(w1 @ x + b1)) in bf16, layout ytb[pixel][64]
__global__ __launch_bounds__(256) void ky(
    const float* __restrict__ x, const float* __restrict__ w1,
    const float* __restrict__ b1, const float* __restrict__ gamma,
    const float* __restrict__ beta, const float* __restrict__ mean,
    const float* __restrict__ var, unsigned short* __restrict__ ytb)
{
    __shared__ float w1t[128 * 68];   // [cl][o], stride 68 (16B-aligned rows)
    const int t = threadIdx.x;
    const int pl = t & 15;            // pixel quad: 4 consecutive pixels
    const int oq = t >> 4;            // 0..15 -> outputs oq*4..+3
    const int bid = blockIdx.x;
    const int b = bid / 49;
    const int pbase = (bid - b * 49) * 64;
    const float* xp = x + (size_t)b * 256 * HW + pbase + pl * 4;

    float acc[4][4];   // [px][o]
#pragma unroll
    for (int i = 0; i < 4; ++i)
#pragma unroll
        for (int j = 0; j < 4; ++j) acc[i][j] = 0.f;

    for (int cb = 0; cb < 2; ++cb) {
        __syncthreads();
        for (int L = t; L < 8192; L += 256) {   // coalesced read, transposed write
            int o = L >> 7, cl = L & 127;
            w1t[cl * 68 + o] = w1[o * 256 + cb * 128 + cl];
        }
        __syncthreads();
#pragma unroll 4
        for (int cl = 0; cl < 128; ++cl) {
            float4 xv = *(const float4*)(xp + (size_t)(cb * 128 + cl) * HW);
            float4 wv = *(const float4*)&w1t[cl * 68 + oq * 4];
            acc[0][0] += xv.x * wv.x; acc[0][1] += xv.x * wv.y;
            acc[0][2] += xv.x * wv.z; acc[0][3] += xv.x * wv.w;
            acc[1][0] += xv.y * wv.x; acc[1][1] += xv.y * wv.y;
            acc[1][2] += xv.y * wv.z; acc[1][3] += xv.y * wv.w;
            acc[2][0] += xv.z * wv.x; acc[2][1] += xv.z * wv.y;
            acc[2][2] += xv.z * wv.z; acc[2][3] += xv.z * wv.w;
            acc[3][0] += xv.w * wv.x; acc[3][1] += xv.w * wv.y;
            acc[3][2] += xv.w * wv.z; acc[3][3] += xv.w * wv.w;
        }
    }

    const int o0 = oq * 4;
    float sc[4], sh[4];
#pragma unroll
    for (int j = 0; j < 4; ++j) {
        float s = gamma[o0 + j] * rsqrtf(var[o0 + j] + 1e-5f);
        sc[j] = s;
        sh[j] = beta[o0 + j] - mean[o0 + j] * s + b1[o0 + j] * s;
    }
#pragma unroll
    for (int i = 0; i < 4; ++i) {
        int Pg = bid * 64 + pl * 4 + i;
        ushort4 r;
        r.x = f2bf(fmaxf(acc[i][0] * sc[0] + sh[0], 0.f));
        r.y = f2bf(fmaxf(acc[i][1] * sc[1] + sh[1], 0.f));
        r.z = f2bf(fmaxf(acc[i][2] * sc[2] + sh[2], 0.f));
        r.w = f2bf(fmaxf(acc[i][3] * sc[3] + sh[3], 0.f));
        *(ushort4*)(ytb + (size_t)Pg * 64 + o0) = r;
    }
}

// Fused: weight = w2b @ y (bf16 MFMA, per 16-pixel tile) + involution.
// Block = 256 threads = 4 waves, 4x4 pixel tile. 4 chunks of 16 groups.
__global__ __launch_bounds__(256, 2) void kmain(
    const float* __restrict__ x, const unsigned short* __restrict__ w2b,
    const float* __restrict__ b2, const unsigned short* __restrict__ ytb,
    float* __restrict__ out)
{
    __shared__ float wgt[784 * 16];   // [chl][pix] fp32, 50 KB
    __shared__ float4 xs4[16 * 110];  // [g][r(10)][s stride 11] x 4 cig, 28 KB
    const int t = threadIdx.x;
    const int pix = t & 15, sub = t >> 4;
    const int lane = t & 63, wave = t >> 6;
    const int b = blockIdx.z, h0 = blockIdx.y * 4, w0 = blockIdx.x * 4;
    const int ph = pix >> 2, pw = pix & 3;
    const int h = h0 + ph, w = w0 + pw;

    // B-fragments: this block's 16 y-vectors (identical in all 4 waves)
    const int n = lane & 15, quad = lane >> 4;
    const int Pn = b * HW + (h0 + (n >> 2)) * 56 + w0 + (n & 3);
    const short8 bf0 = *(const short8*)(ytb + (size_t)Pn * 64 + quad * 8);
    const short8 bf1 = *(const short8*)(ytb + (size_t)Pn * 64 + quad * 8 + 32);

    const int sg = t & 15, sr = t >> 4;   // staging job (g, row), t < 160

    for (int chunk = 0; chunk < 4; ++chunk) {
        if (chunk) __syncthreads();

        // ---- stage x footprint: 64 channels, rows h0-3..h0+6, cols w0-3..w0+6
        if (t < 160) {
            int hh = h0 + sr - 3;
            float4* dst = &xs4[sg * 110 + sr * 11];
            if (hh >= 0 && hh < 56) {
                const float* src = x + ((size_t)b * 256 + chunk * 64 + sg * 4) * HW + hh * 56;
#pragma unroll
                for (int q = 0; q < 3; ++q) {
                    int col0 = w0 - 4 + q * 4;
                    float va[4][4];
                    if (col0 >= 0 && col0 + 3 <= 55) {
#pragma unroll
                        for (int ci = 0; ci < 4; ++ci) {
                            float4 v = *(const float4*)(src + ci * HW + col0);
                            va[ci][0] = v.x; va[ci][1] = v.y;
                            va[ci][2] = v.z; va[ci][3] = v.w;
                        }
                    } else {
#pragma unroll
                        for (int ci = 0; ci < 4; ++ci)
#pragma unroll
                            for (int e = 0; e < 4; ++e) {
                                int col = col0 + e;
                                va[ci][e] = (col >= 0 && col < 56) ? src[ci * HW + col] : 0.f;
                            }
                    }
#pragma unroll
                    for (int e = 0; e < 4; ++e) {
                        int s = q * 4 + e - 1;
                        if (s >= 0 && s <= 9)
                            dst[s] = make_float4(va[0][e], va[1][e], va[2][e], va[3][e]);
                    }
                }
            } else {
#pragma unroll
                for (int s = 0; s < 10; ++s) dst[s] = make_float4(0.f, 0.f, 0.f, 0.f);
            }
        }

        // ---- weight generation: 784 ch x 16 px via MFMA, A streamed from L2
        const int c0 = chunk * 784;
        for (int tile = wave; tile < 49; tile += 4) {
            const unsigned short* ap = w2b + (size_t)(c0 + tile * 16 + n) * 64 + quad * 8;
            short8 af0 = *(const short8*)(ap);
            short8 af1 = *(const short8*)(ap + 32);
            f32x4 acc = {0.f, 0.f, 0.f, 0.f};
            acc = __builtin_amdgcn_mfma_f32_16x16x32_bf16(af0, bf0, acc, 0, 0, 0);
            acc = __builtin_amdgcn_mfma_f32_16x16x32_bf16(af1, bf1, acc, 0, 0, 0);
            int rbase = tile * 16 + quad * 4;
#pragma unroll
            for (int r = 0; r < 4; ++r)
                wgt[(rbase + r) * 16 + n] = acc[r] + b2[c0 + rbase + r];
        }
        __syncthreads();

        // ---- involution: thread owns group (chunk*16+sub), 4 channels, 1 pixel
        const float* wrow = &wgt[sub * 49 * 16 + pix];
        float a0 = 0.f, a1 = 0.f, a2 = 0.f, a3 = 0.f;
#pragma unroll
        for (int ki = 0; ki < 7; ++ki) {
#pragma unroll
            for (int kj = 0; kj < 7; ++kj) {
                float wv = wrow[(ki * 7 + kj) * 16];
                float4 xv = xs4[sub * 110 + (ph + ki) * 11 + (pw + kj)];
                a0 += wv * xv.x; a1 += wv * xv.y;
                a2 += wv * xv.z; a3 += wv * xv.w;
            }
        }
        size_t ob = ((size_t)b * 256 + chunk * 64 + sub * 4) * HW + h * 56 + w;
        out[ob] = a0;
        out[ob + HW] = a1;
        out[ob + 2 * HW] = a2;
        out[ob + 3 * HW] = a3;
    }
}

extern "C" void kernel_launch(void* const* d_in, const int* in_sizes, int n_in,
                              void* d_out, int out_size, void* d_ws, size_t ws_size,
                              hipStream_t stream) {
    const float* x     = (const float*)d_in[0];
    const float* w1    = (const float*)d_in[1];
    const float* b1    = (const float*)d_in[2];
    const float* gamma = (const float*)d_in[3];
    const float* beta  = (const float*)d_in[4];
    const float* mean  = (const float*)d_in[5];
    const float* var   = (const float*)d_in[6];
    const float* w2    = (const float*)d_in[7];
    const float* b2    = (const float*)d_in[8];
    float* out = (float*)d_out;

    unsigned short* ytb = (unsigned short*)d_ws;          // 12544*64 bf16 = 1.53 MB
    unsigned short* w2b = ytb + (size_t)NPX * 64;         // 3136*64 bf16 = 392 KB

    hipLaunchKernelGGL(kprep, dim3(196), dim3(256), 0, stream, w2, w2b);
    hipLaunchKernelGGL(ky, dim3(196), dim3(256), 0, stream,
                       x, w1, b1, gamma, beta, mean, var, ytb);
    hipLaunchKernelGGL(kmain, dim3(14, 14, 4), dim3(256), 0, stream,
                       x, w2b, b2, ytb, out);
}